// Round 9
// baseline (355.073 us; speedup 1.0000x reference)
//
#include <hip/hip_runtime.h>
#include <hip/hip_bf16.h>

#define B_ 4
#define S_ 128
#define D_ 512
#define H_ 8
#define DH_ 64
#define F_ 2048
#define R_ 8

typedef __attribute__((ext_vector_type(8))) short short8;
typedef __attribute__((ext_vector_type(4))) float f32x4;

// fp32 -> bf16 hi (RNE) + bf16 lo (RNE of exact residual)
__device__ __forceinline__ void split2(float a, unsigned short& h, unsigned short& l) {
    unsigned u = __float_as_uint(a);
    unsigned hr = (u + 0x7FFFu + ((u >> 16) & 1u)) >> 16;
    h = (unsigned short)hr;
    float lo = a - __uint_as_float(hr << 16);
    unsigned u2 = __float_as_uint(lo);
    l = (unsigned short)((u2 + 0x7FFFu + ((u2 >> 16) & 1u)) >> 16);
}

// ---------------- weight transpose + bf16 hi/lo split (per call; ws is re-poisoned) ----------------
struct TDesc { const float* s; unsigned short* h; unsigned short* l; int K; int N; int off; };
struct TPack { TDesc d[10]; };

__global__ void transpose_split_kernel(TPack p) {
    __shared__ float sm[32][33];
    int bid = blockIdx.x;
    int wi = 0;
#pragma unroll
    for (int i = 1; i < 10; ++i) if (bid >= p.d[i].off) wi = i;
    const TDesc dd = p.d[wi];
    int t = bid - dd.off;
    int ntk = dd.K / 32;
    int tk = t % ntk, tn = t / ntk;
    int k0 = tk * 32, n0 = tn * 32;
    int col = threadIdx.x & 31, rg = threadIdx.x >> 5;
#pragma unroll
    for (int i = 0; i < 4; ++i) {
        int row = rg * 4 + i;
        sm[row][col] = dd.s[(size_t)(k0 + row) * dd.N + n0 + col];
    }
    __syncthreads();
#pragma unroll
    for (int i = 0; i < 4; ++i) {
        int n = n0 + rg * 4 + i;
        int k = k0 + col;
        float v = sm[col][rg * 4 + i];
        unsigned short h, l;
        split2(v, h, l);
        dd.h[(size_t)n * dd.K + k] = h;
        dd.l[(size_t)n * dd.K + k] = l;
    }
}

// ---------------- MFMA bf16x3 GEMM cores ----------------
// Tile 64x64, BK=32, 4 waves (each 32x32 of 2x2 16x16x32 MFMA).
// LDS pitch 36 ushorts: bank step 18 -> 16 rows all-distinct banks.
#define RPB 36

// A already bf16 hi/lo [M][K] k-contig; B bf16 hi/lo [N][K] k-contig. Register prefetch.
__device__ __forceinline__ void bb_core(const unsigned short* __restrict__ Ath,
                                        const unsigned short* __restrict__ Atl,
                                        const unsigned short* __restrict__ Bth,
                                        const unsigned short* __restrict__ Btl,
                                        int K, int rowBase, int colBase, int kStart, int kLen,
                                        f32x4 acc[2][2],
                                        unsigned short Ah[64][RPB], unsigned short Al[64][RPB],
                                        unsigned short Bh[64][RPB], unsigned short Bl[64][RPB]) {
    int tid = threadIdx.x;
    int w = tid >> 6, lane = tid & 63;
    int lm = lane & 15, quad = lane >> 4;
    int wm = (w & 1) * 32, wn = (w >> 1) * 32;
    int sRow = tid >> 2, sCh = (tid & 3) * 8;
    const size_t aoff = (size_t)(rowBase + sRow) * K + sCh + kStart;
    const size_t boff = (size_t)(colBase + sRow) * K + sCh + kStart;
    int nIter = kLen / 32;
    short8 pah = *(const short8*)&Ath[aoff];
    short8 pal = *(const short8*)&Atl[aoff];
    short8 pbh = *(const short8*)&Bth[boff];
    short8 pbl = *(const short8*)&Btl[boff];
    for (int it = 0; it < nIter; ++it) {
        *(short8*)&Ah[sRow][sCh] = pah;
        *(short8*)&Al[sRow][sCh] = pal;
        *(short8*)&Bh[sRow][sCh] = pbh;
        *(short8*)&Bl[sRow][sCh] = pbl;
        __syncthreads();
        if (it + 1 < nIter) {
            size_t ka = (size_t)(it + 1) * 32;
            pah = *(const short8*)&Ath[aoff + ka];
            pal = *(const short8*)&Atl[aoff + ka];
            pbh = *(const short8*)&Bth[boff + ka];
            pbl = *(const short8*)&Btl[boff + ka];
        }
        short8 ah[2], al[2], bh[2], bl[2];
#pragma unroll
        for (int t = 0; t < 2; ++t) {
            ah[t] = *(const short8*)&Ah[wm + t * 16 + lm][quad * 8];
            al[t] = *(const short8*)&Al[wm + t * 16 + lm][quad * 8];
            bh[t] = *(const short8*)&Bh[wn + t * 16 + lm][quad * 8];
            bl[t] = *(const short8*)&Bl[wn + t * 16 + lm][quad * 8];
        }
#pragma unroll
        for (int tm = 0; tm < 2; ++tm)
#pragma unroll
            for (int tn = 0; tn < 2; ++tn) {
                acc[tm][tn] = __builtin_amdgcn_mfma_f32_16x16x32_bf16(ah[tm], bh[tn], acc[tm][tn], 0, 0, 0);
                acc[tm][tn] = __builtin_amdgcn_mfma_f32_16x16x32_bf16(ah[tm], bl[tn], acc[tm][tn], 0, 0, 0);
                acc[tm][tn] = __builtin_amdgcn_mfma_f32_16x16x32_bf16(al[tm], bh[tn], acc[tm][tn], 0, 0, 0);
            }
        __syncthreads();
    }
}

// A fp32 [M][K] (split in-kernel); B bf16 hi/lo [N][K]. Register prefetch.
__device__ __forceinline__ void fb_core(const float* __restrict__ A,
                                        const unsigned short* __restrict__ Bth,
                                        const unsigned short* __restrict__ Btl,
                                        int K, int rowBase, int colBase, int kStart, int kLen,
                                        f32x4 acc[2][2],
                                        unsigned short Ah[64][RPB], unsigned short Al[64][RPB],
                                        unsigned short Bh[64][RPB], unsigned short Bl[64][RPB]) {
    int tid = threadIdx.x;
    int w = tid >> 6, lane = tid & 63;
    int lm = lane & 15, quad = lane >> 4;
    int wm = (w & 1) * 32, wn = (w >> 1) * 32;
    // A tasks: 64 rows x 8 float4 = 512 -> 2/thread ; B tasks: 64 rows x 4 chunks x 2 prec = 512 -> 2/thread
    int aRow[2], aCh[2], bRow[2], bPrec[2], bCh[2];
#pragma unroll
    for (int i = 0; i < 2; ++i) {
        int ta = tid + i * 256;
        aRow[i] = ta >> 3; aCh[i] = (ta & 7) * 4;
        bRow[i] = ta >> 3;
        int sub = ta & 7;
        bPrec[i] = sub >> 2; bCh[i] = (sub & 3) * 8;
    }
    int nIter = kLen / 32;
    float4 pa[2]; short8 pb[2];
#pragma unroll
    for (int i = 0; i < 2; ++i) {
        pa[i] = *(const float4*)&A[(size_t)(rowBase + aRow[i]) * K + kStart + aCh[i]];
        const unsigned short* bp = bPrec[i] ? Btl : Bth;
        pb[i] = *(const short8*)&bp[(size_t)(colBase + bRow[i]) * K + kStart + bCh[i]];
    }
    for (int it = 0; it < nIter; ++it) {
#pragma unroll
        for (int i = 0; i < 2; ++i) {
            unsigned short h[4], l[4];
            split2(pa[i].x, h[0], l[0]); split2(pa[i].y, h[1], l[1]);
            split2(pa[i].z, h[2], l[2]); split2(pa[i].w, h[3], l[3]);
            unsigned long long ph = (unsigned long long)h[0] | ((unsigned long long)h[1] << 16)
                                  | ((unsigned long long)h[2] << 32) | ((unsigned long long)h[3] << 48);
            unsigned long long pl = (unsigned long long)l[0] | ((unsigned long long)l[1] << 16)
                                  | ((unsigned long long)l[2] << 32) | ((unsigned long long)l[3] << 48);
            *(unsigned long long*)&Ah[aRow[i]][aCh[i]] = ph;
            *(unsigned long long*)&Al[aRow[i]][aCh[i]] = pl;
            unsigned short (*Bd)[RPB] = bPrec[i] ? Bl : Bh;
            *(short8*)&Bd[bRow[i]][bCh[i]] = pb[i];
        }
        __syncthreads();
        if (it + 1 < nIter) {
            int kk = kStart + (it + 1) * 32;
#pragma unroll
            for (int i = 0; i < 2; ++i) {
                pa[i] = *(const float4*)&A[(size_t)(rowBase + aRow[i]) * K + kk + aCh[i]];
                const unsigned short* bp = bPrec[i] ? Btl : Bth;
                pb[i] = *(const short8*)&bp[(size_t)(colBase + bRow[i]) * K + kk + bCh[i]];
            }
        }
        short8 ah[2], al[2], bh[2], bl[2];
#pragma unroll
        for (int t = 0; t < 2; ++t) {
            ah[t] = *(const short8*)&Ah[wm + t * 16 + lm][quad * 8];
            al[t] = *(const short8*)&Al[wm + t * 16 + lm][quad * 8];
            bh[t] = *(const short8*)&Bh[wn + t * 16 + lm][quad * 8];
            bl[t] = *(const short8*)&Bl[wn + t * 16 + lm][quad * 8];
        }
#pragma unroll
        for (int tm = 0; tm < 2; ++tm)
#pragma unroll
            for (int tn = 0; tn < 2; ++tn) {
                acc[tm][tn] = __builtin_amdgcn_mfma_f32_16x16x32_bf16(ah[tm], bh[tn], acc[tm][tn], 0, 0, 0);
                acc[tm][tn] = __builtin_amdgcn_mfma_f32_16x16x32_bf16(ah[tm], bl[tn], acc[tm][tn], 0, 0, 0);
                acc[tm][tn] = __builtin_amdgcn_mfma_f32_16x16x32_bf16(al[tm], bh[tn], acc[tm][tn], 0, 0, 0);
            }
        __syncthreads();
    }
}

// bf16-A,B -> bf16 hi/lo output (full K), bias + optional relu. grid (N/64, M/64)
__global__ __launch_bounds__(256) void mgemm_bb_out16(const unsigned short* __restrict__ Ath,
                                                      const unsigned short* __restrict__ Atl,
                                                      const unsigned short* __restrict__ Bth,
                                                      const unsigned short* __restrict__ Btl,
                                                      const float* __restrict__ bias,
                                                      unsigned short* __restrict__ Ch,
                                                      unsigned short* __restrict__ Cl,
                                                      int N, int K, int relu) {
    __shared__ unsigned short Ah[64][RPB], Al[64][RPB], Bh[64][RPB], Bl[64][RPB];
    int tid = threadIdx.x;
    int w = tid >> 6, lane = tid & 63;
    int lm = lane & 15, quad = lane >> 4;
    int wm = (w & 1) * 32, wn = (w >> 1) * 32;
    int rowBase = blockIdx.y * 64, colBase = blockIdx.x * 64;
    f32x4 acc[2][2] = {};
    bb_core(Ath, Atl, Bth, Btl, K, rowBase, colBase, 0, K, acc, Ah, Al, Bh, Bl);
#pragma unroll
    for (int tm = 0; tm < 2; ++tm)
#pragma unroll
        for (int tn = 0; tn < 2; ++tn) {
            int col = colBase + wn + tn * 16 + lm;
            float bi = bias ? bias[col] : 0.f;
#pragma unroll
            for (int r = 0; r < 4; ++r) {
                int row = rowBase + wm + tm * 16 + quad * 4 + r;
                float v = acc[tm][tn][r] + bi;
                if (relu) v = fmaxf(v, 0.f);
                unsigned short h, l;
                split2(v, h, l);
                Ch[(size_t)row * N + col] = h;
                Cl[(size_t)row * N + col] = l;
            }
        }
}

// bf16-A,B -> fp32 atomicAdd output; grid.z = nW*ks; weight z-stride K*N; bias at kz==0.
__global__ __launch_bounds__(256) void mgemm_bb_atomic(const unsigned short* __restrict__ Ath,
                                                       const unsigned short* __restrict__ Atl,
                                                       const unsigned short* __restrict__ Bth,
                                                       const unsigned short* __restrict__ Btl,
                                                       const float* __restrict__ b0,
                                                       const float* __restrict__ b1,
                                                       const float* __restrict__ b2,
                                                       float* __restrict__ Cbase,
                                                       int M, int N, int K, int ks) {
    __shared__ unsigned short Ah[64][RPB], Al[64][RPB], Bh[64][RPB], Bl[64][RPB];
    int wz = blockIdx.z / ks, kz = blockIdx.z % ks;
    int kLen = K / ks;
    const unsigned short* bth = Bth + (size_t)wz * K * N;
    const unsigned short* btl = Btl + (size_t)wz * K * N;
    const float* bias = (wz == 0) ? b0 : (wz == 1) ? b1 : b2;
    float* C = Cbase + (size_t)wz * M * N;
    int tid = threadIdx.x;
    int w = tid >> 6, lane = tid & 63;
    int lm = lane & 15, quad = lane >> 4;
    int wm = (w & 1) * 32, wn = (w >> 1) * 32;
    int rowBase = blockIdx.y * 64, colBase = blockIdx.x * 64;
    f32x4 acc[2][2] = {};
    bb_core(Ath, Atl, bth, btl, K, rowBase, colBase, kz * kLen, kLen, acc, Ah, Al, Bh, Bl);
#pragma unroll
    for (int tm = 0; tm < 2; ++tm)
#pragma unroll
        for (int tn = 0; tn < 2; ++tn) {
            int col = colBase + wn + tn * 16 + lm;
            float bi = (bias && kz == 0) ? bias[col] : 0.f;
#pragma unroll
            for (int r = 0; r < 4; ++r) {
                int row = rowBase + wm + tm * 16 + quad * 4 + r;
                atomicAdd(&C[(size_t)row * N + col], acc[tm][tn][r] + bi);
            }
        }
}

// fp32-A -> fp32 atomicAdd output; grid.z = nW*ks.
__global__ __launch_bounds__(256) void mgemm_fb_atomic(const float* __restrict__ A,
                                                       const unsigned short* __restrict__ Bth,
                                                       const unsigned short* __restrict__ Btl,
                                                       const float* __restrict__ b0,
                                                       const float* __restrict__ b1,
                                                       float* __restrict__ Cbase,
                                                       int M, int N, int K, int ks) {
    __shared__ unsigned short Ah[64][RPB], Al[64][RPB], Bh[64][RPB], Bl[64][RPB];
    int wz = blockIdx.z / ks, kz = blockIdx.z % ks;
    int kLen = K / ks;
    const unsigned short* bth = Bth + (size_t)wz * K * N;
    const unsigned short* btl = Btl + (size_t)wz * K * N;
    const float* bias = (wz == 0) ? b0 : b1;
    float* C = Cbase + (size_t)wz * M * N;
    int tid = threadIdx.x;
    int w = tid >> 6, lane = tid & 63;
    int lm = lane & 15, quad = lane >> 4;
    int wm = (w & 1) * 32, wn = (w >> 1) * 32;
    int rowBase = blockIdx.y * 64, colBase = blockIdx.x * 64;
    f32x4 acc[2][2] = {};
    fb_core(A, bth, btl, K, rowBase, colBase, kz * kLen, kLen, acc, Ah, Al, Bh, Bl);
#pragma unroll
    for (int tm = 0; tm < 2; ++tm)
#pragma unroll
        for (int tn = 0; tn < 2; ++tn) {
            int col = colBase + wn + tn * 16 + lm;
            float bi = (bias && kz == 0) ? bias[col] : 0.f;
#pragma unroll
            for (int r = 0; r < 4; ++r) {
                int row = rowBase + wm + tm * 16 + quad * 4 + r;
                atomicAdd(&C[(size_t)row * N + col], acc[tm][tn][r] + bi);
            }
        }
}

// ---------------- LayerNorm 1 -> xn bf16 hi/lo ----------------
__global__ void ln1_kernel(const float* __restrict__ x, const float* __restrict__ g,
                           const float* __restrict__ be,
                           unsigned short* __restrict__ xnh, unsigned short* __restrict__ xnl) {
    int row = blockIdx.x;
    int t = threadIdx.x;
    __shared__ float red[256];
    const float* xr = x + row * D_;
    float v0 = xr[t];
    float v1 = xr[t + 256];
    red[t] = v0 + v1;
    __syncthreads();
    for (int off = 128; off > 0; off >>= 1) {
        if (t < off) red[t] += red[t + off];
        __syncthreads();
    }
    float mean = red[0] * (1.0f / D_);
    __syncthreads();
    float d0 = v0 - mean, d1 = v1 - mean;
    red[t] = d0 * d0 + d1 * d1;
    __syncthreads();
    for (int off = 128; off > 0; off >>= 1) {
        if (t < off) red[t] += red[t + off];
        __syncthreads();
    }
    float rs = rsqrtf(red[0] * (1.0f / D_) + 1e-5f);
    float o0 = d0 * rs * g[t] + be[t];
    float o1 = d1 * rs * g[t + 256] + be[t + 256];
    unsigned short h, l;
    split2(o0, h, l); xnh[row * D_ + t] = h; xnl[row * D_ + t] = l;
    split2(o1, h, l); xnh[row * D_ + t + 256] = h; xnl[row * D_ + t + 256] = l;
}

// ---------------- Attention + adjacency fused: one block per (b,i), 8 waves = 8 heads ----------------
__global__ __launch_bounds__(512) void attn_adj_kernel(const float* __restrict__ q,
                                                       const float* __restrict__ k,
                                                       const float* __restrict__ v,
                                                       unsigned short* __restrict__ ctxh,
                                                       unsigned short* __restrict__ ctxl,
                                                       int* __restrict__ ecount,
                                                       int* __restrict__ elist) {
    __shared__ float qsm[H_][DH_];
    __shared__ float psm[H_][S_];
    int w = threadIdx.x >> 6, lane = threadIdx.x & 63;   // w = head
    int bi = blockIdx.x;                                 // b*S + i
    int i = bi & (S_ - 1);
    int b = bi >> 7;
    qsm[w][lane] = q[(size_t)bi * D_ + w * DH_ + lane];
    __syncthreads();
    float s0 = 0.f, s1 = 0.f;
    const float* k0p = k + (size_t)(b * S_ + lane) * D_ + w * DH_;
    const float* k1p = k0p + (size_t)64 * D_;
#pragma unroll 8
    for (int d = 0; d < DH_; ++d) {
        float qd = qsm[w][d];
        s0 += qd * k0p[d];
        s1 += qd * k1p[d];
    }
    s0 *= 0.125f; s1 *= 0.125f;
    float m = fmaxf(s0, s1);
#pragma unroll
    for (int off = 32; off > 0; off >>= 1) m = fmaxf(m, __shfl_xor(m, off));
    float e0 = __expf(s0 - m), e1 = __expf(s1 - m);
    float sum = e0 + e1;
#pragma unroll
    for (int off = 32; off > 0; off >>= 1) sum += __shfl_xor(sum, off);
    float inv = 1.f / sum;
    psm[w][lane] = e0 * inv;
    psm[w][lane + 64] = e1 * inv;
    __syncthreads();
    // adjacency (mean over h, in h order) + compaction: threads 0..127 handle j
    if (threadIdx.x < S_) {
        int j = threadIdx.x;
        float s = psm[0][j];
        s += psm[1][j]; s += psm[2][j]; s += psm[3][j];
        s += psm[4][j]; s += psm[5][j]; s += psm[6][j]; s += psm[7][j];
        s *= 0.125f;
        if (s > 0.1f && j != i) {
            int p = atomicAdd(ecount, 1);
            elist[p] = (bi << 7) | j;
        }
    }
    // ctx for head w, dim lane
    const float* vb = v + (size_t)(b * S_) * D_ + w * DH_ + lane;
    float acc = 0.f;
    for (int j = 0; j < S_; ++j) acc += psm[w][j] * vb[(size_t)j * D_];
    unsigned short h, l;
    split2(acc, h, l);
    ctxh[(size_t)bi * D_ + w * DH_ + lane] = h;
    ctxl[(size_t)bi * D_ + w * DH_ + lane] = l;
}

// ---------------- Relation classifier over compacted edges ----------------
__global__ __launch_bounds__(64) void edge_kernel(const float* __restrict__ a_part,
                                                  const float* __restrict__ b_part,
                                                  const float* __restrict__ rc_b1,
                                                  const float* __restrict__ rc_w2,
                                                  const float* __restrict__ rc_b2,
                                                  const int* __restrict__ elist,
                                                  const int* __restrict__ ecount,
                                                  int* __restrict__ rel) {
    int lane = threadIdx.x;
    int n = *ecount;
    for (int e = blockIdx.x; e < n; e += gridDim.x) {
        int idx = elist[e];
        int vv = idx & (S_ - 1);
        int bu = idx >> 7;
        int u = bu & (S_ - 1);
        int b = bu >> 7;
        const float* ap = a_part + (size_t)(b * S_ + u) * D_;
        const float* bp = b_part + (size_t)(b * S_ + vv) * D_;
        float lp[R_];
#pragma unroll
        for (int r = 0; r < R_; ++r) lp[r] = 0.f;
#pragma unroll
        for (int jj = 0; jj < D_ / 64; ++jj) {
            int d = lane + jj * 64;
            float hv = fmaxf(ap[d] + bp[d] + rc_b1[d], 0.f);
#pragma unroll
            for (int r = 0; r < R_; ++r) lp[r] += hv * rc_w2[d * R_ + r];
        }
#pragma unroll
        for (int r = 0; r < R_; ++r) {
#pragma unroll
            for (int off = 32; off > 0; off >>= 1) lp[r] += __shfl_down(lp[r], off);
        }
        if (lane == 0) {
            float best = lp[0] + rc_b2[0];
            int bi = 0;
#pragma unroll
            for (int r = 1; r < R_; ++r) {
                float L = lp[r] + rc_b2[r];
                if (L > best) { best = L; bi = r; }
            }
            rel[idx] = bi;
        }
    }
}

// ---------------- mbuild: LDS accumulate -> Mbuf bf16 hi/lo ----------------
__global__ __launch_bounds__(128) void mbuild_kernel(const float* __restrict__ nu,
                                                     const int* __restrict__ rel,
                                                     unsigned short* __restrict__ Mh,
                                                     unsigned short* __restrict__ Ml) {
    __shared__ float acc[R_ * D_];   // 16 KB
    __shared__ int rl[S_];
    int blk = blockIdx.x;            // b*S + v
    int vv = blk & (S_ - 1);
    int b = blk >> 7;
    int t = threadIdx.x;             // 128
    for (int i = t; i < R_ * D_; i += 128) acc[i] = 0.f;
    rl[t] = rel[((size_t)b * S_ + t) * S_ + vv];
    __syncthreads();
    for (int u = 0; u < S_; ++u) {
        int r = rl[u];
        if (r > 0) {
            const float* nurow = nu + (size_t)(b * S_ + u) * D_;
            float* arow = acc + r * D_;
#pragma unroll
            for (int jj = 0; jj < D_ / 128; ++jj) arow[t + jj * 128] += nurow[t + jj * 128];
        }
    }
    __syncthreads();
    unsigned short* Mhr = Mh + (size_t)blk * (R_ * D_);
    unsigned short* Mlr = Ml + (size_t)blk * (R_ * D_);
    for (int i = t; i < R_ * D_; i += 128) {
        unsigned short h, l;
        split2(acc[i], h, l);
        Mhr[i] = h; Mlr[i] = l;
    }
}

// ---------------- LayerNorm 2 -> fp32 out ----------------
__global__ void ln2_kernel(const float* __restrict__ x, const float* __restrict__ y,
                           const float* __restrict__ g, const float* __restrict__ be,
                           float* __restrict__ out) {
    int row = blockIdx.x;
    int t = threadIdx.x;
    __shared__ float red[256];
    float v0 = x[row * D_ + t]       + y[row * D_ + t];
    float v1 = x[row * D_ + t + 256] + y[row * D_ + t + 256];
    red[t] = v0 + v1;
    __syncthreads();
    for (int off = 128; off > 0; off >>= 1) {
        if (t < off) red[t] += red[t + off];
        __syncthreads();
    }
    float mean = red[0] * (1.0f / D_);
    __syncthreads();
    float d0 = v0 - mean, d1 = v1 - mean;
    red[t] = d0 * d0 + d1 * d1;
    __syncthreads();
    for (int off = 128; off > 0; off >>= 1) {
        if (t < off) red[t] += red[t + off];
        __syncthreads();
    }
    float rs = rsqrtf(red[0] * (1.0f / D_) + 1e-5f);
    out[row * D_ + t]       = d0 * rs * g[t]       + be[t];
    out[row * D_ + t + 256] = d1 * rs * g[t + 256] + be[t + 256];
}

extern "C" void kernel_launch(void* const* d_in, const int* in_sizes, int n_in,
                              void* d_out, int out_size, void* d_ws, size_t ws_size,
                              hipStream_t stream) {
    const float* x     = (const float*)d_in[0];
    const float* ln1_g = (const float*)d_in[1];
    const float* ln1_b = (const float*)d_in[2];
    const float* wq    = (const float*)d_in[3];
    const float* bq    = (const float*)d_in[4];
    const float* wk    = (const float*)d_in[5];
    const float* bk    = (const float*)d_in[6];
    const float* wv    = (const float*)d_in[7];
    const float* bv    = (const float*)d_in[8];
    const float* wo    = (const float*)d_in[9];
    const float* bo    = (const float*)d_in[10];
    const float* w1    = (const float*)d_in[11];
    const float* b1    = (const float*)d_in[12];
    const float* w2    = (const float*)d_in[13];
    const float* b2    = (const float*)d_in[14];
    const float* rc_w1 = (const float*)d_in[15];
    const float* rc_b1 = (const float*)d_in[16];
    const float* rc_w2 = (const float*)d_in[17];
    const float* rc_b2 = (const float*)d_in[18];
    const float* kg_w  = (const float*)d_in[19];
    const float* s2n_w = (const float*)d_in[20];
    const float* s2n_b = (const float*)d_in[21];
    const float* ln2_g = (const float*)d_in[22];
    const float* ln2_b = (const float*)d_in[23];
    float* out = (float*)d_out;

    const int BS  = B_ * S_;          // 512
    const int BSD = BS * D_;          // 262144

    // ---- Workspace (ws_size = 256 MB; total used ~48 MB) ----
    unsigned short* wt = (unsigned short*)d_ws;
    const size_t E = 262144;          // 512*512
    unsigned short* qkv_h = wt;
    unsigned short* qkv_l = wt + 3 * E;
    unsigned short* wo_h  = wt + 6 * E;
    unsigned short* wo_l  = wt + 7 * E;
    unsigned short* w1_h  = wt + 8 * E;
    unsigned short* w1_l  = wt + 12 * E;
    unsigned short* w2_h  = wt + 16 * E;
    unsigned short* w2_l  = wt + 20 * E;
    unsigned short* rc_h  = wt + 24 * E;
    unsigned short* rc_l  = wt + 26 * E;
    unsigned short* kg_h  = wt + 28 * E;
    unsigned short* kg_l  = wt + 36 * E;
    unsigned short* s2_h  = wt + 44 * E;
    unsigned short* s2_l  = wt + 45 * E;

    // zero zone: q,k,v,nu,a_part,b_part,y (7 x BSD fp32) + rel + ecount — ONE memset
    float* zz = (float*)(wt + 46 * E);
    float* q      = zz;
    float* k      = zz + (size_t)BSD;
    float* v_     = zz + (size_t)2 * BSD;
    float* nu     = zz + (size_t)3 * BSD;
    float* a_part = zz + (size_t)4 * BSD;
    float* y      = zz + (size_t)6 * BSD;   // b_part = a_part + BSD
    int* rel    = (int*)(zz + (size_t)7 * BSD);
    int* ecount = rel + B_ * S_ * S_;
    int* elist  = ecount + 64;              // not zeroed
    unsigned short* act = (unsigned short*)(elist + B_ * S_ * S_);
    unsigned short* xnh  = act;
    unsigned short* xnl  = act + (size_t)BSD;
    unsigned short* ctxh = act + (size_t)2 * BSD;
    unsigned short* ctxl = act + (size_t)3 * BSD;
    unsigned short* aoh  = act + (size_t)4 * BSD;
    unsigned short* aol  = act + (size_t)5 * BSD;
    unsigned short* hidh = act + (size_t)6 * BSD;            // BS*F each
    unsigned short* hidl = hidh + (size_t)BS * F_;
    unsigned short* mbh  = hidl + (size_t)BS * F_;           // BS*R*D each
    unsigned short* mbl  = mbh + (size_t)BS * R_ * D_;

    // 0a. single memset: 7 MB atomic targets + rel + ecount
    hipMemsetAsync(zz, 0, (size_t)7 * BSD * 4 + (size_t)(B_ * S_ * S_ + 64) * 4, stream);
    // 0b. transpose+split weights
    TPack tp;
    int off = 0;
    auto setd = [&](int i, const float* s, unsigned short* h, unsigned short* l, int K, int N) {
        tp.d[i] = TDesc{s, h, l, K, N, off};
        off += (K / 32) * (N / 32);
    };
    setd(0, wq, qkv_h,         qkv_l,         D_, D_);
    setd(1, wk, qkv_h + E,     qkv_l + E,     D_, D_);
    setd(2, wv, qkv_h + 2 * E, qkv_l + 2 * E, D_, D_);
    setd(3, wo, wo_h, wo_l, D_, D_);
    setd(4, w1, w1_h, w1_l, D_, F_);
    setd(5, w2, w2_h, w2_l, F_, D_);
    setd(6, rc_w1,            rc_h,     rc_l,     D_, D_);
    setd(7, rc_w1 + D_ * D_,  rc_h + E, rc_l + E, D_, D_);
    setd(8, kg_w, kg_h, kg_l, R_ * D_, D_);
    setd(9, s2n_w, s2_h, s2_l, D_, D_);
    hipLaunchKernelGGL(transpose_split_kernel, dim3(off), dim3(256), 0, stream, tp);

    // 1. LN1 -> xn hi/lo
    hipLaunchKernelGGL(ln1_kernel, dim3(BS), dim3(256), 0, stream, x, ln1_g, ln1_b, xnh, xnl);
    // 2. QKV: z=3 weights x ks=2 -> 384 blocks, atomic into zeroed q,k,v
    hipLaunchKernelGGL(mgemm_bb_atomic, dim3(D_ / 64, BS / 64, 6), dim3(256), 0, stream,
                       xnh, xnl, qkv_h, qkv_l, bq, bk, bv, q, BS, D_, D_, 2);
    // 3. attention + adjacency fused -> ctx hi/lo, ecount/elist
    hipLaunchKernelGGL(attn_adj_kernel, dim3(BS), dim3(512), 0, stream,
                       q, k, v_, ctxh, ctxl, ecount, elist);
    // 4. wo: ctx -> attn_out hi/lo
    hipLaunchKernelGGL(mgemm_bb_out16, dim3(D_ / 64, BS / 64), dim3(256), 0, stream,
                       ctxh, ctxl, wo_h, wo_l, bo, aoh, aol, D_, D_, 0);
    // 5. FFN1 (relu): attn_out -> hidden hi/lo
    hipLaunchKernelGGL(mgemm_bb_out16, dim3(F_ / 64, BS / 64), dim3(256), 0, stream,
                       aoh, aol, w1_h, w1_l, b1, hidh, hidl, F_, D_, 1);
    // 6. FFN2 ks=4 -> nu (zeroed)
    hipLaunchKernelGGL(mgemm_bb_atomic, dim3(D_ / 64, BS / 64, 4), dim3(256), 0, stream,
                       hidh, hidl, w2_h, w2_l, b2, (const float*)nullptr, (const float*)nullptr,
                       nu, BS, D_, F_, 4);
    // 7. rc halves: z=2 x ks=2 -> a_part,b_part (zeroed); A = nu fp32
    hipLaunchKernelGGL(mgemm_fb_atomic, dim3(D_ / 64, BS / 64, 4), dim3(256), 0, stream,
                       nu, rc_h, rc_l, (const float*)nullptr, (const float*)nullptr,
                       a_part, BS, D_, D_, 2);
    // 8. edges (persistent over compacted list)
    hipLaunchKernelGGL(edge_kernel, dim3(256), dim3(64), 0, stream,
                       a_part, a_part + BSD, rc_b1, rc_w2, rc_b2, elist, ecount, rel);
    // 9. RGCN aggregate -> Mbuf hi/lo
    hipLaunchKernelGGL(mbuild_kernel, dim3(BS), dim3(128), 0, stream, nu, rel, mbh, mbl);
    // 10. Mbuf @ kg_w ks=8, atomicAdd into nu (reasoned = nu + agg)
    hipLaunchKernelGGL(mgemm_bb_atomic, dim3(D_ / 64, BS / 64, 8), dim3(256), 0, stream,
                       mbh, mbl, kg_h, kg_l, (const float*)nullptr, (const float*)nullptr,
                       (const float*)nullptr, nu, BS, D_, R_ * D_, 8);
    // 11. s2n ks=2 -> y (zeroed); A = nu fp32
    hipLaunchKernelGGL(mgemm_fb_atomic, dim3(D_ / 64, BS / 64, 2), dim3(256), 0, stream,
                       nu, s2_h, s2_l, s2n_b, (const float*)nullptr, y, BS, D_, D_, 2);
    // 12. LN2 -> out
    hipLaunchKernelGGL(ln2_kernel, dim3(BS), dim3(256), 0, stream, x, y, ln2_g, ln2_b, out);
}